// Round 4
// baseline (214.893 us; speedup 1.0000x reference)
//
#include <hip/hip_runtime.h>
#include <cstdint>
#include <cstddef>

#define GG 512
#define NF 64
#define EPSF 1e-5f

__device__ __forceinline__ void atomAddF(float* p, float v) {
    unsafeAtomicAdd(p, v);   // hardware global_atomic_add_f32 (no CAS loop)
}

// ---------------- Pass A: per-graph sum / sumsq / count of x00 ----------------
// 64 nodes per wave; fast path: 16 float4 loads batched 8-deep for MLP.
__global__ __launch_bounds__(256, 4) void k_stats(const float* __restrict__ x00, const int* __restrict__ gid,
                        float* __restrict__ gsum, float* __restrict__ gsq,
                        float* __restrict__ gcnt, int N)
{
    int w = (blockIdx.x * blockDim.x + threadIdx.x) >> 6;
    int lane = threadIdx.x & 63;
    long base = (long)w * 64;
    int gf = gid[base];
    int gl = gid[base + 63];
    if (gf == gl) {
        const float4* p = reinterpret_cast<const float4*>(x00 + base * NF) + lane;
        float s0=0,s1=0,s2=0,s3=0,q0=0,q1=0,q2=0,q3=0;
        #pragma unroll
        for (int kc = 0; kc < 16; kc += 8) {
            float4 v[8];
            #pragma unroll
            for (int u = 0; u < 8; ++u) v[u] = p[(kc + u) * 64];
            #pragma unroll
            for (int u = 0; u < 8; ++u) {
                s0+=v[u].x; s1+=v[u].y; s2+=v[u].z; s3+=v[u].w;
                q0=fmaf(v[u].x,v[u].x,q0); q1=fmaf(v[u].y,v[u].y,q1);
                q2=fmaf(v[u].z,v[u].z,q2); q3=fmaf(v[u].w,v[u].w,q3);
            }
        }
        #pragma unroll
        for (int m = 16; m < 64; m <<= 1) {
            s0+=__shfl_xor(s0,m); s1+=__shfl_xor(s1,m); s2+=__shfl_xor(s2,m); s3+=__shfl_xor(s3,m);
            q0+=__shfl_xor(q0,m); q1+=__shfl_xor(q1,m); q2+=__shfl_xor(q2,m); q3+=__shfl_xor(q3,m);
        }
        if (lane < 16) {
            float* ds = gsum + gf * NF + lane * 4;
            float* dq = gsq  + gf * NF + lane * 4;
            atomAddF(ds+0,s0); atomAddF(ds+1,s1); atomAddF(ds+2,s2); atomAddF(ds+3,s3);
            atomAddF(dq+0,q0); atomAddF(dq+1,q1); atomAddF(dq+2,q2); atomAddF(dq+3,q3);
        }
        if (lane == 0) atomAddF(&gcnt[gf], 64.0f);
    } else {
        int myg = gid[base + lane];
        int cur = gf;
        float s = 0.f, q = 0.f, cnt = 0.f;
        for (int k = 0; k < 64; ++k) {
            int g = __shfl(myg, k);
            if (g != cur) {
                atomAddF(&gsum[cur * NF + lane], s);
                atomAddF(&gsq [cur * NF + lane], q);
                if (lane == 0) atomAddF(&gcnt[cur], cnt);
                s = q = cnt = 0.f; cur = g;
            }
            float v = x00[(base + k) * NF + lane];
            s += v; q = fmaf(v, v, q); cnt += 1.f;
        }
        atomAddF(&gsum[cur * NF + lane], s);
        atomAddF(&gsq [cur * NF + lane], q);
        if (lane == 0) atomAddF(&gcnt[cur], cnt);
    }
}

// ------------- Per-graph effective affine weights for logits ------------------
__global__ void k_prep(const float* __restrict__ gsum, const float* __restrict__ gsq,
                       const float* __restrict__ gcnt,
                       const float* __restrict__ gamma, const float* __restrict__ beta,
                       const float* __restrict__ lin_w, const float* __restrict__ lin_b,
                       float* __restrict__ Aeff, float* __restrict__ Beff)
{
    int g = blockIdx.x;
    int c = threadIdx.x;           // 64 threads = 1 wave
    float cnt = fmaxf(gcnt[g], 1.f);
    float mean = gsum[g * NF + c] / cnt;
    float var  = gsq [g * NF + c] / cnt - mean * mean;
    float rs = rsqrtf(var + EPSF);
    float ga = gamma[c], be = beta[c];
    #pragma unroll
    for (int j = 0; j < 3; ++j) {
        float wv = lin_w[j * NF + c];
        Aeff[((long)g * 3 + j) * NF + c] = rs * ga * wv;
        float term = (be - mean * rs * ga) * wv;
        #pragma unroll
        for (int m = 32; m; m >>= 1) term += __shfl_xor(term, m);
        if (c == 0) Beff[g * 3 + j] = term + lin_b[j];
    }
}

// --------- Pass B: logits -> e (no max-shift), pos-weighted sums, e-sums ------
__global__ __launch_bounds__(128, 2) void k_logits(const float* __restrict__ x00, const int* __restrict__ gid,
                         const float* __restrict__ pos,
                         const float* __restrict__ Aeff, const float* __restrict__ Beff,
                         float* __restrict__ ebp, float* __restrict__ accum, int N)
{
    __shared__ float T2[2][64 * 68];
    int wid = threadIdx.x >> 6;
    int lane = threadIdx.x & 63;
    long chunk = (long)blockIdx.x * 2 + wid;
    long base = chunk * 64;
    float* T = T2[wid];

    const float* src = x00 + base * NF;
    {
        float4 vv[16];
        #pragma unroll
        for (int k = 0; k < 16; ++k)
            vv[k] = *reinterpret_cast<const float4*>(src + k * 256 + lane * 4);
        #pragma unroll
        for (int k = 0; k < 16; ++k) {
            int fl = k * 256 + lane * 4;
            int n = fl >> 6, c = fl & 63;
            *reinterpret_cast<float4*>(&T[n * 68 + c]) = vv[k];
        }
    }
    __syncthreads();

    int gf = gid[base], gl = gid[base + 63];
    float l0, l1, l2;
    int g_l;
    if (gf == gl) {
        g_l = gf;
        const float* ap = Aeff + (size_t)gf * 192;
        float a0a=0,a0b=0,a1a=0,a1b=0,a2a=0,a2b=0;
        #pragma unroll
        for (int t = 0; t < 16; ++t) {
            float4 xv = *reinterpret_cast<const float4*>(&T[lane * 68 + 4 * t]);
            float4 w0 = *reinterpret_cast<const float4*>(ap + 4 * t);
            float4 w1 = *reinterpret_cast<const float4*>(ap + 64 + 4 * t);
            float4 w2 = *reinterpret_cast<const float4*>(ap + 128 + 4 * t);
            a0a = fmaf(xv.x,w0.x,fmaf(xv.y,w0.y,a0a)); a0b = fmaf(xv.z,w0.z,fmaf(xv.w,w0.w,a0b));
            a1a = fmaf(xv.x,w1.x,fmaf(xv.y,w1.y,a1a)); a1b = fmaf(xv.z,w1.z,fmaf(xv.w,w1.w,a1b));
            a2a = fmaf(xv.x,w2.x,fmaf(xv.y,w2.y,a2a)); a2b = fmaf(xv.z,w2.z,fmaf(xv.w,w2.w,a2b));
        }
        l0 = a0a + a0b + Beff[gf*3+0];
        l1 = a1a + a1b + Beff[gf*3+1];
        l2 = a2a + a2b + Beff[gf*3+2];
    } else {
        g_l = gid[base + lane];
        const float* ap = Aeff + (size_t)g_l * 192;
        float a0=0,a1=0,a2=0;
        #pragma unroll
        for (int t = 0; t < 16; ++t) {
            float4 xv = *reinterpret_cast<const float4*>(&T[lane * 68 + 4 * t]);
            float4 w0 = *reinterpret_cast<const float4*>(ap + 4 * t);
            float4 w1 = *reinterpret_cast<const float4*>(ap + 64 + 4 * t);
            float4 w2 = *reinterpret_cast<const float4*>(ap + 128 + 4 * t);
            a0 = fmaf(xv.x,w0.x,fmaf(xv.y,w0.y,fmaf(xv.z,w0.z,fmaf(xv.w,w0.w,a0))));
            a1 = fmaf(xv.x,w1.x,fmaf(xv.y,w1.y,fmaf(xv.z,w1.z,fmaf(xv.w,w1.w,a1))));
            a2 = fmaf(xv.x,w2.x,fmaf(xv.y,w2.y,fmaf(xv.z,w2.z,fmaf(xv.w,w2.w,a2))));
        }
        l0 = a0 + Beff[g_l*3+0];
        l1 = a1 + Beff[g_l*3+1];
        l2 = a2 + Beff[g_l*3+2];
    }
    float e0 = expf(l0), e1 = expf(l1), e2 = expf(l2);
    long node = base + lane;
    ebp[node]            = e0;
    ebp[(long)N + node]  = e1;
    ebp[2L * N + node]   = e2;

    const float* pp = pos + node * 6;
    float2 v01 = *reinterpret_cast<const float2*>(pp);
    float2 v23 = *reinterpret_cast<const float2*>(pp + 2);
    float2 v45 = *reinterpret_cast<const float2*>(pp + 4);
    float p0 = v01.x*e2, p1 = v01.y*e2, p2 = v23.x*e2, p3 = v23.y*e2, p4 = v45.x*e2, p5 = v45.y*e2;
    if (gf == gl) {
        #pragma unroll
        for (int m = 1; m < 64; m <<= 1) {
            e0+=__shfl_xor(e0,m); e1+=__shfl_xor(e1,m); e2+=__shfl_xor(e2,m);
            p0+=__shfl_xor(p0,m); p1+=__shfl_xor(p1,m); p2+=__shfl_xor(p2,m);
            p3+=__shfl_xor(p3,m); p4+=__shfl_xor(p4,m); p5+=__shfl_xor(p5,m);
        }
        if (lane == 0) {
            float* dst = accum + (long)gf * 32;
            atomAddF(dst+16,p0); atomAddF(dst+17,p1); atomAddF(dst+18,p2);
            atomAddF(dst+19,p3); atomAddF(dst+20,p4); atomAddF(dst+21,p5);
            atomAddF(dst+22,e0); atomAddF(dst+23,e1); atomAddF(dst+24,e2);
        }
    } else {
        float* dst = accum + (long)g_l * 32;
        atomAddF(dst+16,p0); atomAddF(dst+17,p1); atomAddF(dst+18,p2);
        atomAddF(dst+19,p3); atomAddF(dst+20,p4); atomAddF(dst+21,p5);
        atomAddF(dst+22,e0); atomAddF(dst+23,e1); atomAddF(dst+24,e2);
    }
}

// ---- Pass D: channel-contracted weighted segment sums of x10, x01, x11 -------
// 32 nodes/wave; per-lane feature-quad role; e via one load + shfl broadcast;
// float4 loads batched 8-deep for memory-level parallelism.
__global__ __launch_bounds__(256, 4) void k_wsum(const float* __restrict__ x10, const float* __restrict__ x01,
                       const float* __restrict__ x11,
                       const float* __restrict__ ebp, const int* __restrict__ gid,
                       const float* __restrict__ w10, const float* __restrict__ w01,
                       const float* __restrict__ w11,
                       float* __restrict__ accum, int N)
{
    __shared__ float Tb[4][240];
    int wid = threadIdx.x >> 6;
    int w = (blockIdx.x * blockDim.x + threadIdx.x) >> 6;
    int lane = threadIdx.x & 63;
    long base = (long)w * 32;
    float* T = Tb[wid];

    // lane -> feature-quad role
    const float* p; long stride; int accOff; bool wr = true; bool useE1;
    float wt0, wt1, wt2, wt3;
    if (lane < 12) {
        p = x10 + lane * 4; stride = 48; useE1 = true; accOff = lane * 4;
        int f = lane * 4;
        wt0 = w10[f/3]; wt1 = w10[(f+1)/3]; wt2 = w10[(f+2)/3]; wt3 = w10[(f+3)/3];
    } else if (lane < 24) {
        p = x01 + (lane - 12) * 4; stride = 48; useE1 = true; accOff = 48 + (lane - 12) * 4;
        int f = (lane - 12) * 4;
        wt0 = w01[f/3]; wt1 = w01[(f+1)/3]; wt2 = w01[(f+2)/3]; wt3 = w01[(f+3)/3];
    } else if (lane < 60) {
        p = x11 + (lane - 24) * 4; stride = 144; useE1 = false; accOff = 96 + (lane - 24) * 4;
        int f = (lane - 24) * 4;
        wt0 = w11[f/9]; wt1 = w11[(f+1)/9]; wt2 = w11[(f+2)/9]; wt3 = w11[(f+3)/9];
    } else {
        p = x11 + 140; stride = 144; useE1 = false; accOff = 0; wr = false;
        wt0 = wt1 = wt2 = wt3 = 0.f;
    }

    // e broadcast source: lanes 0..31 hold e0[base+l], lanes 32..63 hold e1[base+l-32]
    int l31 = lane & 31;
    float er = (lane < 32) ? ebp[base + l31] : ebp[(long)N + base + l31];
    int bidx = useE1 ? 32 : 0;

    float a0=0,a1=0,a2=0,a3=0;
    const float* pp = p + base * stride;

    auto flush = [&](int g) {
        asm volatile("" ::: "memory");
        if (wr) {
            T[accOff+0] = a0*wt0; T[accOff+1] = a1*wt1;
            T[accOff+2] = a2*wt2; T[accOff+3] = a3*wt3;
        }
        asm volatile("s_waitcnt lgkmcnt(0)" ::: "memory");
        if (lane < 15) {
            int off, strd;
            if (lane < 3)      { off = lane;            strd = 3; }
            else if (lane < 6) { off = 48 + (lane - 3); strd = 3; }
            else               { off = 96 + (lane - 6); strd = 9; }
            float s = 0.f;
            #pragma unroll
            for (int c = 0; c < 16; ++c) s += T[off + c * strd];
            atomAddF(accum + (long)g * 32 + lane, s);
        }
        asm volatile("s_waitcnt lgkmcnt(0)" ::: "memory");
    };

    int gf = gid[base], gl = gid[base + 31];
    if (gf == gl) {
        #pragma unroll
        for (int kc = 0; kc < 32; kc += 8) {
            float4 v[8];
            #pragma unroll
            for (int u = 0; u < 8; ++u)
                v[u] = *reinterpret_cast<const float4*>(pp + (size_t)(kc + u) * stride);
            #pragma unroll
            for (int u = 0; u < 8; ++u) {
                float e = __shfl(er, bidx + kc + u);
                a0 = fmaf(v[u].x,e,a0); a1 = fmaf(v[u].y,e,a1);
                a2 = fmaf(v[u].z,e,a2); a3 = fmaf(v[u].w,e,a3);
            }
        }
        flush(gf);
    } else {
        int myg = gid[base + l31];
        int cur = gf;
        for (int k = 0; k < 32; ++k) {
            int g = __shfl(myg, k);
            if (g != cur) { flush(cur); a0=a1=a2=a3=0.f; cur = g; }
            float e = __shfl(er, bidx + k);
            float4 v = *reinterpret_cast<const float4*>(pp + (size_t)k * stride);
            a0 = fmaf(v.x,e,a0); a1 = fmaf(v.y,e,a1); a2 = fmaf(v.z,e,a2); a3 = fmaf(v.w,e,a3);
        }
        flush(cur);
    }
}

// --------------------------- Pass E: per-graph epilogue -----------------------
#define JROT(p, q) do { \
    float apq_ = S[p][q]; \
    if (fabsf(apq_) > 1e-20f) { \
        float app_ = S[p][p], aqq_ = S[q][q]; \
        float tau_ = (aqq_ - app_) / (2.0f * apq_); \
        float tt_ = copysignf(1.0f, tau_) / (fabsf(tau_) + sqrtf(1.0f + tau_ * tau_)); \
        float cc_ = 1.0f / sqrtf(1.0f + tt_ * tt_); \
        float ssn_ = tt_ * cc_; \
        _Pragma("unroll") for (int kk = 0; kk < 3; ++kk) { \
            float skp = S[kk][p], skq = S[kk][q]; \
            S[kk][p] = cc_ * skp - ssn_ * skq; S[kk][q] = ssn_ * skp + cc_ * skq; } \
        _Pragma("unroll") for (int kk = 0; kk < 3; ++kk) { \
            float spk = S[p][kk], sqk = S[q][kk]; \
            S[p][kk] = cc_ * spk - ssn_ * sqk; S[q][kk] = ssn_ * spk + cc_ * sqk; } \
        _Pragma("unroll") for (int kk = 0; kk < 3; ++kk) { \
            float vkp = V[kk][p], vkq = V[kk][q]; \
            V[kk][p] = cc_ * vkp - ssn_ * vkq; V[kk][q] = ssn_ * vkp + cc_ * vkq; } \
    } \
} while (0)

__global__ void k_final(const float* __restrict__ accum, float* __restrict__ out)
{
    int g = blockIdx.x * blockDim.x + threadIdx.x;
    if (g >= GG) return;
    const float* A_ = accum + (long)g * 32;
    float i0 = 1.f / A_[22], i1 = 1.f / A_[23], i2 = 1.f / A_[24];

    float o10[3], o01[3], o11[9];
    #pragma unroll
    for (int d = 0; d < 3; ++d) { o10[d] = A_[d] * i1; o01[d] = A_[3 + d] * i1; }
    #pragma unroll
    for (int d = 0; d < 9; ++d) o11[d] = A_[6 + d] * i0;

    float m1v[3], m2v[3];
    #pragma unroll
    for (int d = 0; d < 3; ++d) { m1v[d] = A_[16 + d] * i2; m2v[d] = A_[19 + d] * i2; }

    int sig[3]; sig[0] = 2; sig[1] = 0; sig[2] = 1;   // Q_MAT permutation
    float rv[9];
    #pragma unroll
    for (int a = 0; a < 3; ++a)
        #pragma unroll
        for (int b = 0; b < 3; ++b)
            rv[a * 3 + b] = o11[sig[a] * 3 + sig[b]];
    float ta[3], tb[3];
    #pragma unroll
    for (int a = 0; a < 3; ++a) { ta[a] = o10[sig[a]]; tb[a] = o01[sig[a]]; }

    float nn = 0.f;
    #pragma unroll
    for (int k = 0; k < 9; ++k) nn += rv[k] * rv[k];
    float invn = 1.f / fmaxf(sqrtf(nn), 1e-5f);
    float M[3][3];
    #pragma unroll
    for (int a = 0; a < 3; ++a)
        #pragma unroll
        for (int b = 0; b < 3; ++b)
            M[a][b] = rv[b * 3 + a] * invn;

    float S[3][3], V[3][3];
    #pragma unroll
    for (int a = 0; a < 3; ++a)
        #pragma unroll
        for (int b = 0; b < 3; ++b) {
            float acc = 0.f;
            #pragma unroll
            for (int k = 0; k < 3; ++k) acc += M[k][a] * M[k][b];
            S[a][b] = acc;
            V[a][b] = (a == b) ? 1.f : 0.f;
        }
    for (int sw = 0; sw < 12; ++sw) { JROT(0, 1); JROT(0, 2); JROT(1, 2); }

    float l0 = S[0][0], l1 = S[1][1], l2 = S[2][2];
    float e0x = V[0][0], e0y = V[1][0], e0z = V[2][0];
    float e1x = V[0][1], e1y = V[1][1], e1z = V[2][1];
    float e2x = V[0][2], e2y = V[1][2], e2z = V[2][2];
    float tfl;
    if (l0 < l1) { tfl=l0;l0=l1;l1=tfl; tfl=e0x;e0x=e1x;e1x=tfl; tfl=e0y;e0y=e1y;e1y=tfl; tfl=e0z;e0z=e1z;e1z=tfl; }
    if (l0 < l2) { tfl=l0;l0=l2;l2=tfl; tfl=e0x;e0x=e2x;e2x=tfl; tfl=e0y;e0y=e2y;e2y=tfl; tfl=e0z;e0z=e2z;e2z=tfl; }
    if (l1 < l2) { tfl=l1;l1=l2;l2=tfl; tfl=e1x;e1x=e2x;e2x=tfl; tfl=e1y;e1y=e2y;e2y=tfl; tfl=e1z;e1z=e2z;e2z=tfl; }

    float c2x = e0y * e1z - e0z * e1y;
    float c2y = e0z * e1x - e0x * e1z;
    float c2z = e0x * e1y - e0y * e1x;
    float cn = rsqrtf(fmaxf(c2x * c2x + c2y * c2y + c2z * c2z, 1e-30f));
    c2x *= cn; c2y *= cn; c2z *= cn;

    float u0x = M[0][0] * e0x + M[0][1] * e0y + M[0][2] * e0z;
    float u0y = M[1][0] * e0x + M[1][1] * e0y + M[1][2] * e0z;
    float u0z = M[2][0] * e0x + M[2][1] * e0y + M[2][2] * e0z;
    float un = rsqrtf(fmaxf(u0x * u0x + u0y * u0y + u0z * u0z, 1e-30f));
    u0x *= un; u0y *= un; u0z *= un;
    float u1x = M[0][0] * e1x + M[0][1] * e1y + M[0][2] * e1z;
    float u1y = M[1][0] * e1x + M[1][1] * e1y + M[1][2] * e1z;
    float u1z = M[2][0] * e1x + M[2][1] * e1y + M[2][2] * e1z;
    float dp = u0x * u1x + u0y * u1y + u0z * u1z;
    u1x -= dp * u0x; u1y -= dp * u0y; u1z -= dp * u0z;
    un = rsqrtf(fmaxf(u1x * u1x + u1y * u1y + u1z * u1z, 1e-30f));
    u1x *= un; u1y *= un; u1z *= un;
    float u2x = u0y * u1z - u0z * u1y;
    float u2y = u0z * u1x - u0x * u1z;
    float u2z = u0x * u1y - u0y * u1x;

    float R[3][3];
    R[0][0] = u0x * e0x + u1x * e1x + u2x * c2x;
    R[0][1] = u0x * e0y + u1x * e1y + u2x * c2y;
    R[0][2] = u0x * e0z + u1x * e1z + u2x * c2z;
    R[1][0] = u0y * e0x + u1y * e1x + u2y * c2x;
    R[1][1] = u0y * e0y + u1y * e1y + u2y * c2y;
    R[1][2] = u0y * e0z + u1y * e1z + u2y * c2z;
    R[2][0] = u0z * e0x + u1z * e1x + u2z * c2x;
    R[2][1] = u0z * e0y + u1z * e1y + u2z * c2y;
    R[2][2] = u0z * e0z + u1z * e1z + u2z * c2z;

    float tv[3];
    #pragma unroll
    for (int a = 0; a < 3; ++a) {
        float acc = m2v[a] + tb[a];
        #pragma unroll
        for (int b = 0; b < 3; ++b) acc -= R[a][b] * (m1v[b] + ta[b]);
        tv[a] = acc;
    }

    #pragma unroll
    for (int k = 0; k < 9; ++k) out[(long)g * 9 + k] = R[k / 3][k % 3];
    #pragma unroll
    for (int a = 0; a < 3; ++a) out[(long)GG * 9 + (long)g * 3 + a] = tv[a];
    #pragma unroll
    for (int k = 0; k < 9; ++k) out[(long)GG * 12 + (long)g * 9 + k] = rv[k];
}

extern "C" void kernel_launch(void* const* d_in, const int* in_sizes, int n_in,
                              void* d_out, int out_size, void* d_ws, size_t ws_size,
                              hipStream_t stream)
{
    const float* x00   = (const float*)d_in[0];
    const float* x10   = (const float*)d_in[1];
    const float* x01   = (const float*)d_in[2];
    const float* x11   = (const float*)d_in[3];
    const float* pos   = (const float*)d_in[4];
    const int*   gid   = (const int*)d_in[5];
    const float* gamma = (const float*)d_in[7];
    const float* beta  = (const float*)d_in[8];
    const float* lin_w = (const float*)d_in[9];
    const float* lin_b = (const float*)d_in[10];
    const float* w10   = (const float*)d_in[11];
    const float* w01   = (const float*)d_in[12];
    const float* w11   = (const float*)d_in[13];
    float* out = (float*)d_out;

    const int N = in_sizes[0] / NF;   // 262144

    // workspace layout (floats)
    float* ws = (float*)d_ws;
    float* gsum  = ws;                       // GG*64
    float* gsq   = gsum + GG * 64;           // GG*64
    float* gcnt  = gsq + GG * 64;            // GG
    float* accum = gcnt + GG;                // GG*32
    float* Aeff  = accum + GG * 32;          // GG*192
    float* Beff  = Aeff + GG * 192;          // GG*3
    float* ebp   = Beff + GG * 3;            // 3*N (planar)

    size_t zeroBytes = (size_t)(GG * 64 * 2 + GG + GG * 32) * sizeof(float);
    hipMemsetAsync(d_ws, 0, zeroBytes, stream);

    int blocksA = (N / 64) / 4;               // 1024 (4 waves/block, 64 nodes/wave)
    int blocksL = (N / 64) / 2;               // 2048 (2 chunks/block)
    int blocksW = (N / 32) / 4;               // 2048 (4 waves/block, 32 nodes/wave)

    k_stats <<<blocksA, 256, 0, stream>>>(x00, gid, gsum, gsq, gcnt, N);
    k_prep  <<<GG, 64, 0, stream>>>(gsum, gsq, gcnt, gamma, beta, lin_w, lin_b, Aeff, Beff);
    k_logits<<<blocksL, 128, 0, stream>>>(x00, gid, pos, Aeff, Beff, ebp, accum, N);
    k_wsum  <<<blocksW, 256, 0, stream>>>(x10, x01, x11, ebp, gid, w10, w01, w11, accum, N);
    k_final <<<(GG + 63) / 64, 64, 0, stream>>>(accum, out);
}

// Round 5
// 173.954 us; speedup vs baseline: 1.2353x; 1.2353x over previous
//
#include <hip/hip_runtime.h>
#include <cstdint>
#include <cstddef>

#define GG 512
#define NF 64
#define EPSF 1e-5f

__device__ __forceinline__ void atomAddF(float* p, float v) {
    unsafeAtomicAdd(p, v);   // hardware global_atomic_add_f32
}

// ---------------- Pass A: per-graph sum / sumsq / count of x00 ----------------
__global__ __launch_bounds__(256) void k_stats(const float* __restrict__ x00, const int* __restrict__ gid,
                        float* __restrict__ gsum, float* __restrict__ gsq,
                        float* __restrict__ gcnt, int N)
{
    int w = (blockIdx.x * blockDim.x + threadIdx.x) >> 6;
    int lane = threadIdx.x & 63;
    long base = (long)w * 64;
    int gf = gid[base];
    int gl = gid[base + 63];
    if (gf == gl) {
        const float4* p = reinterpret_cast<const float4*>(x00 + base * NF) + lane;
        float s0=0,s1=0,s2=0,s3=0,q0=0,q1=0,q2=0,q3=0;
        #pragma unroll
        for (int k = 0; k < 16; ++k) {
            float4 v = p[k * 64];
            s0+=v.x; s1+=v.y; s2+=v.z; s3+=v.w;
            q0=fmaf(v.x,v.x,q0); q1=fmaf(v.y,v.y,q1); q2=fmaf(v.z,v.z,q2); q3=fmaf(v.w,v.w,q3);
        }
        #pragma unroll
        for (int m = 16; m < 64; m <<= 1) {
            s0+=__shfl_xor(s0,m); s1+=__shfl_xor(s1,m); s2+=__shfl_xor(s2,m); s3+=__shfl_xor(s3,m);
            q0+=__shfl_xor(q0,m); q1+=__shfl_xor(q1,m); q2+=__shfl_xor(q2,m); q3+=__shfl_xor(q3,m);
        }
        if (lane < 16) {
            float* ds = gsum + gf * NF + lane * 4;
            float* dq = gsq  + gf * NF + lane * 4;
            atomAddF(ds+0,s0); atomAddF(ds+1,s1); atomAddF(ds+2,s2); atomAddF(ds+3,s3);
            atomAddF(dq+0,q0); atomAddF(dq+1,q1); atomAddF(dq+2,q2); atomAddF(dq+3,q3);
        }
        if (lane == 0) atomAddF(&gcnt[gf], 64.0f);
    } else {
        int myg = gid[base + lane];
        int cur = gf;
        float s = 0.f, q = 0.f, cnt = 0.f;
        for (int k = 0; k < 64; ++k) {
            int g = __shfl(myg, k);
            if (g != cur) {
                atomAddF(&gsum[cur * NF + lane], s);
                atomAddF(&gsq [cur * NF + lane], q);
                if (lane == 0) atomAddF(&gcnt[cur], cnt);
                s = q = cnt = 0.f; cur = g;
            }
            float v = x00[(base + k) * NF + lane];
            s += v; q = fmaf(v, v, q); cnt += 1.f;
        }
        atomAddF(&gsum[cur * NF + lane], s);
        atomAddF(&gsq [cur * NF + lane], q);
        if (lane == 0) atomAddF(&gcnt[cur], cnt);
    }
}

// ------------- Per-graph effective affine weights for logits ------------------
__global__ void k_prep(const float* __restrict__ gsum, const float* __restrict__ gsq,
                       const float* __restrict__ gcnt,
                       const float* __restrict__ gamma, const float* __restrict__ beta,
                       const float* __restrict__ lin_w, const float* __restrict__ lin_b,
                       float* __restrict__ Aeff, float* __restrict__ Beff)
{
    int g = blockIdx.x;
    int c = threadIdx.x;           // 64 threads = 1 wave
    float cnt = fmaxf(gcnt[g], 1.f);
    float mean = gsum[g * NF + c] / cnt;
    float var  = gsq [g * NF + c] / cnt - mean * mean;
    float rs = rsqrtf(var + EPSF);
    float ga = gamma[c], be = beta[c];
    #pragma unroll
    for (int j = 0; j < 3; ++j) {
        float wv = lin_w[j * NF + c];
        Aeff[((long)g * 3 + j) * NF + c] = rs * ga * wv;
        float term = (be - mean * rs * ga) * wv;
        #pragma unroll
        for (int m = 32; m; m >>= 1) term += __shfl_xor(term, m);
        if (c == 0) Beff[g * 3 + j] = term + lin_b[j];
    }
}

// --------- Pass B: logits -> e (no max-shift), pos-weighted sums, e-sums ------
__global__ __launch_bounds__(128) void k_logits(const float* __restrict__ x00, const int* __restrict__ gid,
                         const float* __restrict__ pos,
                         const float* __restrict__ Aeff, const float* __restrict__ Beff,
                         float* __restrict__ ebp, float* __restrict__ accum, int N)
{
    __shared__ float T2[2][64 * 68];
    int wid = threadIdx.x >> 6;
    int lane = threadIdx.x & 63;
    long chunk = (long)blockIdx.x * 2 + wid;
    long base = chunk * 64;
    float* T = T2[wid];

    const float* src = x00 + base * NF;
    #pragma unroll
    for (int k = 0; k < 16; ++k) {
        int fl = k * 256 + lane * 4;
        float4 v = *reinterpret_cast<const float4*>(src + fl);
        int n = fl >> 6, c = fl & 63;
        *reinterpret_cast<float4*>(&T[n * 68 + c]) = v;
    }
    __syncthreads();

    int gf = gid[base], gl = gid[base + 63];
    float l0, l1, l2;
    int g_l;
    if (gf == gl) {
        g_l = gf;
        const float* ap = Aeff + (size_t)gf * 192;
        float a0a=0,a0b=0,a1a=0,a1b=0,a2a=0,a2b=0;
        #pragma unroll
        for (int t = 0; t < 16; ++t) {
            float4 xv = *reinterpret_cast<const float4*>(&T[lane * 68 + 4 * t]);
            float4 w0 = *reinterpret_cast<const float4*>(ap + 4 * t);
            float4 w1 = *reinterpret_cast<const float4*>(ap + 64 + 4 * t);
            float4 w2 = *reinterpret_cast<const float4*>(ap + 128 + 4 * t);
            a0a = fmaf(xv.x,w0.x,fmaf(xv.y,w0.y,a0a)); a0b = fmaf(xv.z,w0.z,fmaf(xv.w,w0.w,a0b));
            a1a = fmaf(xv.x,w1.x,fmaf(xv.y,w1.y,a1a)); a1b = fmaf(xv.z,w1.z,fmaf(xv.w,w1.w,a1b));
            a2a = fmaf(xv.x,w2.x,fmaf(xv.y,w2.y,a2a)); a2b = fmaf(xv.z,w2.z,fmaf(xv.w,w2.w,a2b));
        }
        l0 = a0a + a0b + Beff[gf*3+0];
        l1 = a1a + a1b + Beff[gf*3+1];
        l2 = a2a + a2b + Beff[gf*3+2];
    } else {
        g_l = gid[base + lane];
        const float* ap = Aeff + (size_t)g_l * 192;
        float a0=0,a1=0,a2=0;
        #pragma unroll
        for (int t = 0; t < 16; ++t) {
            float4 xv = *reinterpret_cast<const float4*>(&T[lane * 68 + 4 * t]);
            float4 w0 = *reinterpret_cast<const float4*>(ap + 4 * t);
            float4 w1 = *reinterpret_cast<const float4*>(ap + 64 + 4 * t);
            float4 w2 = *reinterpret_cast<const float4*>(ap + 128 + 4 * t);
            a0 = fmaf(xv.x,w0.x,fmaf(xv.y,w0.y,fmaf(xv.z,w0.z,fmaf(xv.w,w0.w,a0))));
            a1 = fmaf(xv.x,w1.x,fmaf(xv.y,w1.y,fmaf(xv.z,w1.z,fmaf(xv.w,w1.w,a1))));
            a2 = fmaf(xv.x,w2.x,fmaf(xv.y,w2.y,fmaf(xv.z,w2.z,fmaf(xv.w,w2.w,a2))));
        }
        l0 = a0 + Beff[g_l*3+0];
        l1 = a1 + Beff[g_l*3+1];
        l2 = a2 + Beff[g_l*3+2];
    }
    float e0 = expf(l0), e1 = expf(l1), e2 = expf(l2);
    long node = base + lane;
    ebp[node]            = e0;
    ebp[(long)N + node]  = e1;
    ebp[2L * N + node]   = e2;

    const float* pp = pos + node * 6;
    float2 v01 = *reinterpret_cast<const float2*>(pp);
    float2 v23 = *reinterpret_cast<const float2*>(pp + 2);
    float2 v45 = *reinterpret_cast<const float2*>(pp + 4);
    float p0 = v01.x*e2, p1 = v01.y*e2, p2 = v23.x*e2, p3 = v23.y*e2, p4 = v45.x*e2, p5 = v45.y*e2;
    if (gf == gl) {
        #pragma unroll
        for (int m = 1; m < 64; m <<= 1) {
            e0+=__shfl_xor(e0,m); e1+=__shfl_xor(e1,m); e2+=__shfl_xor(e2,m);
            p0+=__shfl_xor(p0,m); p1+=__shfl_xor(p1,m); p2+=__shfl_xor(p2,m);
            p3+=__shfl_xor(p3,m); p4+=__shfl_xor(p4,m); p5+=__shfl_xor(p5,m);
        }
        if (lane == 0) {
            float* dst = accum + (long)gf * 32;
            atomAddF(dst+16,p0); atomAddF(dst+17,p1); atomAddF(dst+18,p2);
            atomAddF(dst+19,p3); atomAddF(dst+20,p4); atomAddF(dst+21,p5);
            atomAddF(dst+22,e0); atomAddF(dst+23,e1); atomAddF(dst+24,e2);
        }
    } else {
        float* dst = accum + (long)g_l * 32;
        atomAddF(dst+16,p0); atomAddF(dst+17,p1); atomAddF(dst+18,p2);
        atomAddF(dst+19,p3); atomAddF(dst+20,p4); atomAddF(dst+21,p5);
        atomAddF(dst+22,e0); atomAddF(dst+23,e1); atomAddF(dst+24,e2);
    }
}

// ---- Pass D1: x11 contraction. Contiguous 1KB wave-bursts -> LDS tile ->
// per-lane (n,d) pairs, register accumulation per graph-run, LDS-reduced flush.
__global__ __launch_bounds__(256) void k_w11(const float* __restrict__ x11,
        const float* __restrict__ ebp, const int* __restrict__ gid,
        const float* __restrict__ w11, float* __restrict__ accum, int N)
{
    __shared__ float LDx[4][16 * 148];
    __shared__ float FLs[4][144];
    int wid = threadIdx.x >> 6;
    int lane = threadIdx.x & 63;
    int wgl = (blockIdx.x * blockDim.x + threadIdx.x) >> 6;
    long nodeBase = (long)wgl * 64;          // 4 tiles of 16 nodes
    float* LD = LDx[wid];
    float* F  = FLs[wid];

    float wv[16];
    #pragma unroll
    for (int c = 0; c < 16; ++c) wv[c] = w11[c];

    int n0 = lane / 9,        d0 = lane % 9;
    int n1 = (lane + 64) / 9, d1 = (lane + 64) % 9;
    int n2 = (lane + 128) / 9, d2 = (lane + 128) % 9;   // valid lane<16
    float acc0 = 0.f, acc1 = 0.f, acc2 = 0.f;

    int cur = gid[nodeBase];

    auto flushW = [&](int g) {
        asm volatile("" ::: "memory");
        F[lane] = acc0; F[64 + lane] = acc1;
        if (lane < 16) F[128 + lane] = acc2;
        asm volatile("s_waitcnt lgkmcnt(0)" ::: "memory");
        if (lane < 9) {
            float s = 0.f;
            #pragma unroll
            for (int m = 0; m < 16; ++m) s += F[m * 9 + lane];
            atomAddF(accum + (long)g * 32 + 6 + lane, s);
        }
        asm volatile("s_waitcnt lgkmcnt(0)" ::: "memory");
        acc0 = acc1 = acc2 = 0.f;
    };

    for (int t = 0; t < 4; ++t) {
        long tb = nodeBase + t * 16;
        const float4* src = reinterpret_cast<const float4*>(x11 + tb * 144);
        #pragma unroll
        for (int u = 0; u < 9; ++u) {
            int i = lane + 64 * u;
            float4 v = src[i];
            int fi = 4 * i;
            int n = fi / 144, k = fi % 144;
            *reinterpret_cast<float4*>(&LD[n * 148 + k]) = v;
        }
        asm volatile("s_waitcnt lgkmcnt(0)" ::: "memory");

        int gf = gid[tb], gl2 = gid[tb + 15];
        float y0 = 0.f, y1 = 0.f, y2 = 0.f;
        #pragma unroll
        for (int c = 0; c < 16; ++c) {
            y0 = fmaf(wv[c], LD[n0 * 148 + c * 9 + d0], y0);
            y1 = fmaf(wv[c], LD[n1 * 148 + c * 9 + d1], y1);
            if (lane < 16) y2 = fmaf(wv[c], LD[n2 * 148 + c * 9 + d2], y2);
        }
        if (gf == gl2) {
            if (gf != cur) { flushW(cur); cur = gf; }
            acc0 = fmaf(ebp[tb + n0], y0, acc0);
            acc1 = fmaf(ebp[tb + n1], y1, acc1);
            if (lane < 16) acc2 = fmaf(ebp[tb + n2], y2, acc2);
        } else {
            flushW(cur);
            atomAddF(accum + (long)gid[tb + n0] * 32 + 6 + d0, ebp[tb + n0] * y0);
            atomAddF(accum + (long)gid[tb + n1] * 32 + 6 + d1, ebp[tb + n1] * y1);
            if (lane < 16)
                atomAddF(accum + (long)gid[tb + n2] * 32 + 6 + d2, ebp[tb + n2] * y2);
            cur = gl2;
        }
        asm volatile("s_waitcnt lgkmcnt(0)" ::: "memory");
    }
    flushW(cur);
}

// ---- Pass D2: x10 & x01 contraction, same contiguous-burst structure --------
__global__ __launch_bounds__(256) void k_w1001(const float* __restrict__ x10,
        const float* __restrict__ x01, const float* __restrict__ ebp,
        const int* __restrict__ gid,
        const float* __restrict__ w10, const float* __restrict__ w01,
        float* __restrict__ accum, int N)
{
    __shared__ float LDx[4][1600];          // x10 rows n*50, x01 at 800+n*50
    __shared__ float FLs[4][96];
    int wid = threadIdx.x >> 6;
    int lane = threadIdx.x & 63;
    int wgl = (blockIdx.x * blockDim.x + threadIdx.x) >> 6;
    long nodeBase = (long)wgl * 64;
    float* LD = LDx[wid];
    float* F  = FLs[wid];

    // pair0 (all lanes): lane<48 -> x10 pair p=lane; else x01 pair j=lane-48
    // pair1 (lane<32): x01 pair j=16+lane
    bool isB0 = (lane >= 48);
    int j0 = isB0 ? (lane - 48) : lane;
    int na0 = j0 / 3, da0 = j0 % 3;
    int off0 = isB0 ? 800 : 0;
    int aout0 = isB0 ? 3 : 0;
    int j1 = 16 + lane;                     // valid lane<32
    int na1 = j1 / 3, da1 = j1 % 3;

    float wv0[16], wv1[16];
    #pragma unroll
    for (int c = 0; c < 16; ++c) {
        wv0[c] = isB0 ? w01[c] : w10[c];
        wv1[c] = w01[c];
    }

    float acc0 = 0.f, acc1 = 0.f;
    int cur = gid[nodeBase];
    const float* e1p = ebp + N;

    auto flushW = [&](int g) {
        asm volatile("" ::: "memory");
        F[lane] = acc0;
        if (lane < 32) F[64 + lane] = acc1;
        asm volatile("s_waitcnt lgkmcnt(0)" ::: "memory");
        if (lane < 6) {
            int d = (lane < 3) ? lane : (lane - 3);
            int bo = (lane < 3) ? 0 : 48;
            float s = 0.f;
            #pragma unroll
            for (int m = 0; m < 16; ++m) s += F[bo + m * 3 + d];
            atomAddF(accum + (long)g * 32 + lane, s);
        }
        asm volatile("s_waitcnt lgkmcnt(0)" ::: "memory");
        acc0 = acc1 = 0.f;
    };

    for (int t = 0; t < 4; ++t) {
        long tb = nodeBase + t * 16;
        const float4* sa = reinterpret_cast<const float4*>(x10 + tb * 48);
        const float4* sb = reinterpret_cast<const float4*>(x01 + tb * 48);
        #pragma unroll
        for (int u = 0; u < 3; ++u) {
            int i = lane + 64 * u;
            float4 va = sa[i];
            float4 vb = sb[i];
            int fi = 4 * i;
            int n = fi / 48, k = fi % 48;
            *reinterpret_cast<float4*>(&LD[n * 50 + k]) = va;
            *reinterpret_cast<float4*>(&LD[800 + n * 50 + k]) = vb;
        }
        asm volatile("s_waitcnt lgkmcnt(0)" ::: "memory");

        int gf = gid[tb], gl2 = gid[tb + 15];
        float y0 = 0.f, y1 = 0.f;
        #pragma unroll
        for (int c = 0; c < 16; ++c) {
            y0 = fmaf(wv0[c], LD[off0 + na0 * 50 + c * 3 + da0], y0);
            if (lane < 32) y1 = fmaf(wv1[c], LD[800 + na1 * 50 + c * 3 + da1], y1);
        }
        if (gf == gl2) {
            if (gf != cur) { flushW(cur); cur = gf; }
            acc0 = fmaf(e1p[tb + na0], y0, acc0);
            if (lane < 32) acc1 = fmaf(e1p[tb + na1], y1, acc1);
        } else {
            flushW(cur);
            atomAddF(accum + (long)gid[tb + na0] * 32 + aout0 + da0, e1p[tb + na0] * y0);
            if (lane < 32)
                atomAddF(accum + (long)gid[tb + na1] * 32 + 3 + da1, e1p[tb + na1] * y1);
            cur = gl2;
        }
        asm volatile("s_waitcnt lgkmcnt(0)" ::: "memory");
    }
    flushW(cur);
}

// --------------------------- Pass E: per-graph epilogue -----------------------
#define JROT(p, q) do { \
    float apq_ = S[p][q]; \
    if (fabsf(apq_) > 1e-20f) { \
        float app_ = S[p][p], aqq_ = S[q][q]; \
        float tau_ = (aqq_ - app_) / (2.0f * apq_); \
        float tt_ = copysignf(1.0f, tau_) / (fabsf(tau_) + sqrtf(1.0f + tau_ * tau_)); \
        float cc_ = 1.0f / sqrtf(1.0f + tt_ * tt_); \
        float ssn_ = tt_ * cc_; \
        _Pragma("unroll") for (int kk = 0; kk < 3; ++kk) { \
            float skp = S[kk][p], skq = S[kk][q]; \
            S[kk][p] = cc_ * skp - ssn_ * skq; S[kk][q] = ssn_ * skp + cc_ * skq; } \
        _Pragma("unroll") for (int kk = 0; kk < 3; ++kk) { \
            float spk = S[p][kk], sqk = S[q][kk]; \
            S[p][kk] = cc_ * spk - ssn_ * sqk; S[q][kk] = ssn_ * spk + cc_ * sqk; } \
        _Pragma("unroll") for (int kk = 0; kk < 3; ++kk) { \
            float vkp = V[kk][p], vkq = V[kk][q]; \
            V[kk][p] = cc_ * vkp - ssn_ * vkq; V[kk][q] = ssn_ * vkp + cc_ * vkq; } \
    } \
} while (0)

__global__ void k_final(const float* __restrict__ accum, float* __restrict__ out)
{
    int g = blockIdx.x * blockDim.x + threadIdx.x;
    if (g >= GG) return;
    const float* A_ = accum + (long)g * 32;
    float i0 = 1.f / A_[22], i1 = 1.f / A_[23], i2 = 1.f / A_[24];

    float o10[3], o01[3], o11[9];
    #pragma unroll
    for (int d = 0; d < 3; ++d) { o10[d] = A_[d] * i1; o01[d] = A_[3 + d] * i1; }
    #pragma unroll
    for (int d = 0; d < 9; ++d) o11[d] = A_[6 + d] * i0;

    float m1v[3], m2v[3];
    #pragma unroll
    for (int d = 0; d < 3; ++d) { m1v[d] = A_[16 + d] * i2; m2v[d] = A_[19 + d] * i2; }

    int sig[3]; sig[0] = 2; sig[1] = 0; sig[2] = 1;   // Q_MAT permutation
    float rv[9];
    #pragma unroll
    for (int a = 0; a < 3; ++a)
        #pragma unroll
        for (int b = 0; b < 3; ++b)
            rv[a * 3 + b] = o11[sig[a] * 3 + sig[b]];
    float ta[3], tb[3];
    #pragma unroll
    for (int a = 0; a < 3; ++a) { ta[a] = o10[sig[a]]; tb[a] = o01[sig[a]]; }

    float nn = 0.f;
    #pragma unroll
    for (int k = 0; k < 9; ++k) nn += rv[k] * rv[k];
    float invn = 1.f / fmaxf(sqrtf(nn), 1e-5f);
    float M[3][3];
    #pragma unroll
    for (int a = 0; a < 3; ++a)
        #pragma unroll
        for (int b = 0; b < 3; ++b)
            M[a][b] = rv[b * 3 + a] * invn;

    float S[3][3], V[3][3];
    #pragma unroll
    for (int a = 0; a < 3; ++a)
        #pragma unroll
        for (int b = 0; b < 3; ++b) {
            float acc = 0.f;
            #pragma unroll
            for (int k = 0; k < 3; ++k) acc += M[k][a] * M[k][b];
            S[a][b] = acc;
            V[a][b] = (a == b) ? 1.f : 0.f;
        }
    for (int sw = 0; sw < 12; ++sw) { JROT(0, 1); JROT(0, 2); JROT(1, 2); }

    float l0 = S[0][0], l1 = S[1][1], l2 = S[2][2];
    float e0x = V[0][0], e0y = V[1][0], e0z = V[2][0];
    float e1x = V[0][1], e1y = V[1][1], e1z = V[2][1];
    float e2x = V[0][2], e2y = V[1][2], e2z = V[2][2];
    float tfl;
    if (l0 < l1) { tfl=l0;l0=l1;l1=tfl; tfl=e0x;e0x=e1x;e1x=tfl; tfl=e0y;e0y=e1y;e1y=tfl; tfl=e0z;e0z=e1z;e1z=tfl; }
    if (l0 < l2) { tfl=l0;l0=l2;l2=tfl; tfl=e0x;e0x=e2x;e2x=tfl; tfl=e0y;e0y=e2y;e2y=tfl; tfl=e0z;e0z=e2z;e2z=tfl; }
    if (l1 < l2) { tfl=l1;l1=l2;l2=tfl; tfl=e1x;e1x=e2x;e2x=tfl; tfl=e1y;e1y=e2y;e2y=tfl; tfl=e1z;e1z=e2z;e2z=tfl; }

    float c2x = e0y * e1z - e0z * e1y;
    float c2y = e0z * e1x - e0x * e1z;
    float c2z = e0x * e1y - e0y * e1x;
    float cn = rsqrtf(fmaxf(c2x * c2x + c2y * c2y + c2z * c2z, 1e-30f));
    c2x *= cn; c2y *= cn; c2z *= cn;

    float u0x = M[0][0] * e0x + M[0][1] * e0y + M[0][2] * e0z;
    float u0y = M[1][0] * e0x + M[1][1] * e0y + M[1][2] * e0z;
    float u0z = M[2][0] * e0x + M[2][1] * e0y + M[2][2] * e0z;
    float un = rsqrtf(fmaxf(u0x * u0x + u0y * u0y + u0z * u0z, 1e-30f));
    u0x *= un; u0y *= un; u0z *= un;
    float u1x = M[0][0] * e1x + M[0][1] * e1y + M[0][2] * e1z;
    float u1y = M[1][0] * e1x + M[1][1] * e1y + M[1][2] * e1z;
    float u1z = M[2][0] * e1x + M[2][1] * e1y + M[2][2] * e1z;
    float dp = u0x * u1x + u0y * u1y + u0z * u1z;
    u1x -= dp * u0x; u1y -= dp * u0y; u1z -= dp * u0z;
    un = rsqrtf(fmaxf(u1x * u1x + u1y * u1y + u1z * u1z, 1e-30f));
    u1x *= un; u1y *= un; u1z *= un;
    float u2x = u0y * u1z - u0z * u1y;
    float u2y = u0z * u1x - u0x * u1z;
    float u2z = u0x * u1y - u0y * u1x;

    float R[3][3];
    R[0][0] = u0x * e0x + u1x * e1x + u2x * c2x;
    R[0][1] = u0x * e0y + u1x * e1y + u2x * c2y;
    R[0][2] = u0x * e0z + u1x * e1z + u2x * c2z;
    R[1][0] = u0y * e0x + u1y * e1x + u2y * c2x;
    R[1][1] = u0y * e0y + u1y * e1y + u2y * c2y;
    R[1][2] = u0y * e0z + u1y * e1z + u2y * c2z;
    R[2][0] = u0z * e0x + u1z * e1x + u2z * c2x;
    R[2][1] = u0z * e0y + u1z * e1y + u2z * c2y;
    R[2][2] = u0z * e0z + u1z * e1z + u2z * c2z;

    float tv[3];
    #pragma unroll
    for (int a = 0; a < 3; ++a) {
        float acc = m2v[a] + tb[a];
        #pragma unroll
        for (int b = 0; b < 3; ++b) acc -= R[a][b] * (m1v[b] + ta[b]);
        tv[a] = acc;
    }

    #pragma unroll
    for (int k = 0; k < 9; ++k) out[(long)g * 9 + k] = R[k / 3][k % 3];
    #pragma unroll
    for (int a = 0; a < 3; ++a) out[(long)GG * 9 + (long)g * 3 + a] = tv[a];
    #pragma unroll
    for (int k = 0; k < 9; ++k) out[(long)GG * 12 + (long)g * 9 + k] = rv[k];
}

extern "C" void kernel_launch(void* const* d_in, const int* in_sizes, int n_in,
                              void* d_out, int out_size, void* d_ws, size_t ws_size,
                              hipStream_t stream)
{
    const float* x00   = (const float*)d_in[0];
    const float* x10   = (const float*)d_in[1];
    const float* x01   = (const float*)d_in[2];
    const float* x11   = (const float*)d_in[3];
    const float* pos   = (const float*)d_in[4];
    const int*   gid   = (const int*)d_in[5];
    const float* gamma = (const float*)d_in[7];
    const float* beta  = (const float*)d_in[8];
    const float* lin_w = (const float*)d_in[9];
    const float* lin_b = (const float*)d_in[10];
    const float* w10   = (const float*)d_in[11];
    const float* w01   = (const float*)d_in[12];
    const float* w11   = (const float*)d_in[13];
    float* out = (float*)d_out;

    const int N = in_sizes[0] / NF;   // 262144

    // workspace layout (floats)
    float* ws = (float*)d_ws;
    float* gsum  = ws;                       // GG*64
    float* gsq   = gsum + GG * 64;           // GG*64
    float* gcnt  = gsq + GG * 64;            // GG
    float* accum = gcnt + GG;                // GG*32
    float* Aeff  = accum + GG * 32;          // GG*192
    float* Beff  = Aeff + GG * 192;          // GG*3
    float* ebp   = Beff + GG * 3;            // 3*N (planar)

    size_t zeroBytes = (size_t)(GG * 64 * 2 + GG + GG * 32) * sizeof(float);
    hipMemsetAsync(d_ws, 0, zeroBytes, stream);

    int blocksA = (N / 64) / 4;               // 1024
    int blocksL = (N / 64) / 2;               // 2048
    int blocksW = (N / 64) / 4;               // 1024 (1 wave = 64 nodes = 4 tiles)

    k_stats <<<blocksA, 256, 0, stream>>>(x00, gid, gsum, gsq, gcnt, N);
    k_prep  <<<GG, 64, 0, stream>>>(gsum, gsq, gcnt, gamma, beta, lin_w, lin_b, Aeff, Beff);
    k_logits<<<blocksL, 128, 0, stream>>>(x00, gid, pos, Aeff, Beff, ebp, accum, N);
    k_w11   <<<blocksW, 256, 0, stream>>>(x11, ebp, gid, w11, accum, N);
    k_w1001 <<<blocksW, 256, 0, stream>>>(x10, x01, ebp, gid, w10, w01, accum, N);
    k_final <<<(GG + 63) / 64, 64, 0, stream>>>(accum, out);
}